// Round 1
// baseline (562.965 us; speedup 1.0000x reference)
//
#include <hip/hip_runtime.h>

typedef unsigned short u16;
typedef __attribute__((ext_vector_type(8))) short v8s;   // 8 x bf16 MFMA operand
typedef __attribute__((ext_vector_type(4))) float v4f;   // MFMA accumulator

__device__ __forceinline__ u16 f2bf(float f) {
  unsigned u = __float_as_uint(f);
  u += 0x7FFF + ((u >> 16) & 1);   // RNE
  return (u16)(u >> 16);
}

__device__ __forceinline__ v4f zero4() {
  v4f z; z[0] = 0.f; z[1] = 0.f; z[2] = 0.f; z[3] = 0.f; return z;
}

__device__ __forceinline__ void async16(const u16* g, u16* l) {
  __builtin_amdgcn_global_load_lds(
      (const __attribute__((address_space(1))) unsigned int*)g,
      (__attribute__((address_space(3))) unsigned int*)l, 16, 0, 0);
}

// reduce x to [-pi,pi] then native sin/cos (v_sin valid range)
__device__ __forceinline__ void fast_sincos(float x, float* s, float* c) {
  float k = rintf(x * 0.15915494309189535f);
  float r = __builtin_fmaf(k, -6.28125f, x);
  r = __builtin_fmaf(k, -0.0019353071795864769f, r);
  *s = __sinf(r);
  *c = __cosf(r);
}

// ---------------- fp32 -> bf16 cast ----------------
__global__ __launch_bounds__(256) void cast_bf16_k(const float* __restrict__ s,
                                                   u16* __restrict__ d, int n4) {
  int i = blockIdx.x * 256 + threadIdx.x;
  if (i >= n4) return;
  float4 v = ((const float4*)s)[i];
  ((ushort4*)d)[i] = make_ushort4(f2bf(v.x), f2bf(v.y), f2bf(v.z), f2bf(v.w));
}

// ---------------- shared GEMM mainloop ----------------
// C(128x128) = A[M,K] @ B[N,K]^T   (both bf16 row-major, K multiple of 64)
// block 256 thr = 4 waves (2x2), each wave 64x64 via 4x4 16x16x32 MFMAs
__device__ __forceinline__ void gemm_core(const u16* __restrict__ A,
                                          const u16* __restrict__ B, int K,
                                          int row0, int col0, u16* As, u16* Bs,
                                          v4f acc[4][4]) {
  const int tid = threadIdx.x;
  const int lane = tid & 63;
  const int wm = (tid >> 7) & 1;
  const int wn = (tid >> 6) & 1;
  const int ln = lane & 15, quad = lane >> 4;
#pragma unroll
  for (int i = 0; i < 4; ++i)
#pragma unroll
    for (int j = 0; j < 4; ++j) acc[i][j] = zero4();
  const int rA = tid >> 3;          // 0..31 (row within 32-row chunk)
  const int cA = (tid & 7) * 8;     // k element offset
  for (int kt = 0; kt < K; kt += 64) {
#pragma unroll
    for (int i = 0; i < 4; ++i) {
      async16(A + (size_t)(row0 + i * 32 + rA) * K + kt + cA, As + i * 2048 + tid * 8);
      async16(B + (size_t)(col0 + i * 32 + rA) * K + kt + cA, Bs + i * 2048 + tid * 8);
    }
    __syncthreads();
#pragma unroll
    for (int kk = 0; kk < 2; ++kk) {
      v8s af[4], bfr[4];
#pragma unroll
      for (int i = 0; i < 4; ++i) {
        af[i]  = *(const v8s*)(As + (wm * 64 + i * 16 + ln) * 64 + kk * 32 + quad * 8);
        bfr[i] = *(const v8s*)(Bs + (wn * 64 + i * 16 + ln) * 64 + kk * 32 + quad * 8);
      }
#pragma unroll
      for (int i = 0; i < 4; ++i)
#pragma unroll
        for (int j = 0; j < 4; ++j)
          acc[i][j] = __builtin_amdgcn_mfma_f32_16x16x32_bf16(af[i], bfr[j], acc[i][j], 0, 0, 0);
    }
    __syncthreads();
  }
}

// ---------------- QKV GEMM + fused RoPE/reshape epilogue ----------------
// A = x_bf16 [8192,1024], B = w_qkv_bf16 [3072,1024]
// q -> Qh[bh][t][64], k -> Kh[bh][t][64] (RoPE'd), v -> Vt[bh][64][2048] (transposed)
__global__ __launch_bounds__(256) void gemm_qkv_rope(const u16* __restrict__ A,
                                                     const u16* __restrict__ B,
                                                     u16* __restrict__ Qh,
                                                     u16* __restrict__ Kh,
                                                     u16* __restrict__ Vt) {
  __shared__ __align__(16) u16 As[8192];
  __shared__ __align__(16) u16 Bs[8192];
  v4f acc[4][4];
  const int row0 = blockIdx.x * 128, col0 = blockIdx.y * 128;
  gemm_core(A, B, 1024, row0, col0, As, Bs, acc);
  const int tid = threadIdx.x, lane = tid & 63;
  const int wm = (tid >> 7) & 1, wn = (tid >> 6) & 1;
  const int ln = lane & 15, quad = lane >> 4;
  const int colbase = col0 + wn * 64;       // 64-aligned => one head per wave
  const int seg = colbase >> 10;            // 0=q 1=k 2=v
  const int h = (colbase & 1023) >> 6;
  if (seg < 2) {
    u16* dst = (seg == 0) ? Qh : Kh;
#pragma unroll
    for (int i = 0; i < 4; ++i) {
#pragma unroll
      for (int r = 0; r < 4; ++r) {
        int row = row0 + wm * 64 + i * 16 + quad * 4 + r;
        int b = row >> 11, t = row & 2047;
        size_t base = ((size_t)(b * 16 + h) * 2048 + t) * 64;
#pragma unroll
        for (int j = 0; j < 2; ++j) {
          int d1 = j * 16 + ln;  // 0..31
          float theta = exp2f((float)d1 * -0.4152410118609203f);  // 10000^(-d1/32)
          float sn, cs;
          fast_sincos((float)t * theta, &sn, &cs);
          float v1 = acc[i][j][r], v2 = acc[i][j + 2][r];
          dst[base + d1]      = f2bf(v1 * cs - v2 * sn);
          dst[base + d1 + 32] = f2bf(v2 * cs + v1 * sn);
        }
      }
    }
  } else {
#pragma unroll
    for (int i = 0; i < 4; ++i)
#pragma unroll
      for (int j = 0; j < 4; ++j) {
        int d = j * 16 + ln;
#pragma unroll
        for (int r = 0; r < 4; ++r) {
          int row = row0 + wm * 64 + i * 16 + quad * 4 + r;
          int b = row >> 11, t = row & 2047;
          Vt[((size_t)(b * 16 + h) * 64 + d) * 2048 + t] = f2bf(acc[i][j][r]);
        }
      }
  }
}

// ---------------- output GEMM ----------------
__global__ __launch_bounds__(256) void gemm_out_k(const u16* __restrict__ A,
                                                  const u16* __restrict__ B,
                                                  float* __restrict__ C) {
  __shared__ __align__(16) u16 As[8192];
  __shared__ __align__(16) u16 Bs[8192];
  v4f acc[4][4];
  const int row0 = blockIdx.x * 128, col0 = blockIdx.y * 128;
  gemm_core(A, B, 1024, row0, col0, As, Bs, acc);
  const int tid = threadIdx.x, lane = tid & 63;
  const int wm = (tid >> 7) & 1, wn = (tid >> 6) & 1;
  const int ln = lane & 15, quad = lane >> 4;
#pragma unroll
  for (int i = 0; i < 4; ++i)
#pragma unroll
    for (int r = 0; r < 4; ++r) {
      int row = row0 + wm * 64 + i * 16 + quad * 4 + r;
#pragma unroll
      for (int j = 0; j < 4; ++j) {
        int col = col0 + wn * 64 + j * 16 + ln;
        C[(size_t)row * 1024 + col] = acc[i][j][r];
      }
    }
}

// ---------------- causal flash attention ----------------
// Q,K: [64][2048][64] bf16 ; V: [64][64][2048] bf16 (transposed) ; O: [8192][1024] bf16
// block: 64 q rows (4 waves x 16), key tiles of 32, online softmax
__global__ __launch_bounds__(256) void flash_k(const u16* __restrict__ Q,
                                               const u16* __restrict__ Kh,
                                               const u16* __restrict__ V,
                                               u16* __restrict__ O) {
  __shared__ __align__(16) u16 Qs[64 * 64];
  __shared__ __align__(16) u16 Ks[32 * 64];
  __shared__ __align__(16) u16 Vs[64 * 32];   // [d][key]
  __shared__ __align__(16) u16 Ps[4 * 16 * 32];
  const int tid = threadIdx.x;
  const int lane = tid & 63, w = tid >> 6;
  const int ln = lane & 15, quad = lane >> 4;
  const int qb = blockIdx.x * 64;
  const int bh = blockIdx.y;
  const int b = bh >> 4, h = bh & 15;
  const size_t qoff = (size_t)bh * 2048 * 64;

  {  // stage Q tile (64x64)
    const uint4* qg = (const uint4*)(Q + qoff + (size_t)qb * 64);
    uint4* qs = (uint4*)Qs;
#pragma unroll
    for (int i = 0; i < 2; ++i) qs[tid + i * 256] = qg[tid + i * 256];
  }
  __syncthreads();
  v8s aq[2];
#pragma unroll
  for (int kk = 0; kk < 2; ++kk)
    aq[kk] = *(const v8s*)(Qs + (w * 16 + ln) * 64 + kk * 32 + quad * 8);

  v4f od[4];
  float m_r[4], l_r[4];
#pragma unroll
  for (int r = 0; r < 4; ++r) { m_r[r] = -3.0e38f; l_r[r] = 0.f; }
#pragma unroll
  for (int dt = 0; dt < 4; ++dt) od[dt] = zero4();

  const float SCL = 0.125f * 1.4426950408889634f;  // 1/sqrt(64) * log2(e)
  const int send = qb + 64;
  for (int s0 = 0; s0 < send; s0 += 32) {
    {  // stage K tile (32x64) and V^T tile (64x32)
      *(uint4*)(Ks + tid * 8) = *(const uint4*)(Kh + qoff + (size_t)s0 * 64 + tid * 8);
      int vd = tid >> 2, vc = (tid & 3) * 8;
      *(uint4*)(Vs + vd * 32 + vc) =
          *(const uint4*)(V + (size_t)bh * 131072 + (size_t)vd * 2048 + s0 + vc);
    }
    __syncthreads();
    v4f sc0 = zero4(), sc1 = zero4();
#pragma unroll
    for (int kk = 0; kk < 2; ++kk) {
      v8s b0 = *(const v8s*)(Ks + ln * 64 + kk * 32 + quad * 8);
      v8s b1 = *(const v8s*)(Ks + (16 + ln) * 64 + kk * 32 + quad * 8);
      sc0 = __builtin_amdgcn_mfma_f32_16x16x32_bf16(aq[kk], b0, sc0, 0, 0, 0);
      sc1 = __builtin_amdgcn_mfma_f32_16x16x32_bf16(aq[kk], b1, sc1, 0, 0, 0);
    }
    float sv[2][4];
#pragma unroll
    for (int r = 0; r < 4; ++r) {
      int qrow = qb + w * 16 + quad * 4 + r;
      sv[0][r] = (s0 + ln <= qrow) ? sc0[r] * SCL : -3.0e38f;
      sv[1][r] = (s0 + 16 + ln <= qrow) ? sc1[r] * SCL : -3.0e38f;
    }
    float rmax[4];
#pragma unroll
    for (int r = 0; r < 4; ++r) rmax[r] = fmaxf(sv[0][r], sv[1][r]);
#pragma unroll
    for (int off = 8; off >= 1; off >>= 1)
#pragma unroll
      for (int r = 0; r < 4; ++r) rmax[r] = fmaxf(rmax[r], __shfl_xor(rmax[r], off));
    float p[2][4], rsum[4];
#pragma unroll
    for (int r = 0; r < 4; ++r) {
      float mn = fmaxf(m_r[r], rmax[r]);
      float al = exp2f(m_r[r] - mn);
      m_r[r] = mn;
      p[0][r] = exp2f(sv[0][r] - mn);
      p[1][r] = exp2f(sv[1][r] - mn);
      rsum[r] = p[0][r] + p[1][r];
      l_r[r] *= al;
#pragma unroll
      for (int dt = 0; dt < 4; ++dt) od[dt][r] *= al;
    }
#pragma unroll
    for (int off = 8; off >= 1; off >>= 1)
#pragma unroll
      for (int r = 0; r < 4; ++r) rsum[r] += __shfl_xor(rsum[r], off);
#pragma unroll
    for (int r = 0; r < 4; ++r) l_r[r] += rsum[r];
    // P (C-layout) -> per-wave LDS -> A-layout bf16
    u16* pw = Ps + w * 512;
#pragma unroll
    for (int r = 0; r < 4; ++r) {
      pw[(quad * 4 + r) * 32 + ln]      = f2bf(p[0][r]);
      pw[(quad * 4 + r) * 32 + 16 + ln] = f2bf(p[1][r]);
    }
    __syncthreads();
    v8s ap = *(const v8s*)(pw + ln * 32 + quad * 8);
#pragma unroll
    for (int dt = 0; dt < 4; ++dt) {
      v8s bv = *(const v8s*)(Vs + (dt * 16 + ln) * 32 + quad * 8);
      od[dt] = __builtin_amdgcn_mfma_f32_16x16x32_bf16(ap, bv, od[dt], 0, 0, 0);
    }
    __syncthreads();
  }
#pragma unroll
  for (int r = 0; r < 4; ++r) {
    float inv = 1.0f / l_r[r];
    int t = qb + w * 16 + quad * 4 + r;
    size_t obase = ((size_t)b * 2048 + t) * 1024 + h * 64;
#pragma unroll
    for (int dt = 0; dt < 4; ++dt)
      O[obase + dt * 16 + ln] = f2bf(od[dt][r] * inv);
  }
}

extern "C" void kernel_launch(void* const* d_in, const int* in_sizes, int n_in,
                              void* d_out, int out_size, void* d_ws, size_t ws_size,
                              hipStream_t stream) {
  const float* x     = (const float*)d_in[0];
  const float* w_qkv = (const float*)d_in[1];
  const float* w_out = (const float*)d_in[2];
  float* out = (float*)d_out;
  char* ws = (char*)d_ws;
  // workspace layout (bytes)
  u16* xb    = (u16*)(ws);              // 8M  bf16 (16 MB)
  u16* wqkvb = (u16*)(ws + 16777216);   // 3M  bf16 (6 MB)
  u16* woutb = (u16*)(ws + 23068672);   // 1M  bf16 (2 MB)
  u16* qh    = (u16*)(ws + 25165824);   // [64][2048][64] (16 MB)
  u16* kh    = (u16*)(ws + 41943040);   // [64][2048][64] (16 MB)
  u16* vt    = (u16*)(ws + 58720256);   // [64][64][2048] (16 MB)
  u16* oa    = (u16*)(ws + 75497472);   // [8192][1024]   (16 MB)

  cast_bf16_k<<<8192, 256, 0, stream>>>(x, xb, 2097152);
  cast_bf16_k<<<3072, 256, 0, stream>>>(w_qkv, wqkvb, 786432);
  cast_bf16_k<<<1024, 256, 0, stream>>>(w_out, woutb, 262144);
  gemm_qkv_rope<<<dim3(64, 24), 256, 0, stream>>>(xb, wqkvb, qh, kh, vt);
  flash_k<<<dim3(32, 64), 256, 0, stream>>>(qh, kh, vt, oa);
  gemm_out_k<<<dim3(64, 8), 256, 0, stream>>>(oa, woutb, out);
}

// Round 2
// 562.149 us; speedup vs baseline: 1.0015x; 1.0015x over previous
//
#include <hip/hip_runtime.h>

typedef unsigned short u16;
typedef __attribute__((ext_vector_type(8))) short v8s;   // 8 x bf16 MFMA operand
typedef __attribute__((ext_vector_type(4))) float v4f;   // MFMA accumulator

__device__ __forceinline__ u16 f2bf(float f) {
  unsigned u = __float_as_uint(f);
  u += 0x7FFF + ((u >> 16) & 1);   // RNE
  return (u16)(u >> 16);
}

// pack two floats -> {hi.bf16, lo.bf16} u32, round-to-nearest (bias 0x8000)
__device__ __forceinline__ unsigned pk2bf(float lo, float hi) {
  unsigned a = __float_as_uint(lo) + 0x8000u;
  unsigned b = __float_as_uint(hi) + 0x8000u;
  return __builtin_amdgcn_perm(b, a, 0x07060302);
}

__device__ __forceinline__ v4f zero4() {
  v4f z; z[0] = 0.f; z[1] = 0.f; z[2] = 0.f; z[3] = 0.f; return z;
}

__device__ __forceinline__ void async16(const u16* g, u16* l) {
  __builtin_amdgcn_global_load_lds(
      (const __attribute__((address_space(1))) unsigned int*)g,
      (__attribute__((address_space(3))) unsigned int*)l, 16, 0, 0);
}

// reduce x to [-pi,pi] then native sin/cos (v_sin valid range)
__device__ __forceinline__ void fast_sincos(float x, float* s, float* c) {
  float k = rintf(x * 0.15915494309189535f);
  float r = __builtin_fmaf(k, -6.28125f, x);
  r = __builtin_fmaf(k, -0.0019353071795864769f, r);
  *s = __sinf(r);
  *c = __cosf(r);
}

// ---------------- fp32 -> bf16 cast ----------------
__global__ __launch_bounds__(256) void cast_bf16_k(const float* __restrict__ s,
                                                   u16* __restrict__ d, int n4) {
  int i = blockIdx.x * 256 + threadIdx.x;
  if (i >= n4) return;
  float4 v = ((const float4*)s)[i];
  ((ushort4*)d)[i] = make_ushort4(f2bf(v.x), f2bf(v.y), f2bf(v.z), f2bf(v.w));
}

// ---------------- shared GEMM mainloop ----------------
// C(128x128) = A[M,K] @ B[N,K]^T   (both bf16 row-major, K multiple of 64)
__device__ __forceinline__ void gemm_core(const u16* __restrict__ A,
                                          const u16* __restrict__ B, int K,
                                          int row0, int col0, u16* As, u16* Bs,
                                          v4f acc[4][4]) {
  const int tid = threadIdx.x;
  const int lane = tid & 63;
  const int wm = (tid >> 7) & 1;
  const int wn = (tid >> 6) & 1;
  const int ln = lane & 15, quad = lane >> 4;
#pragma unroll
  for (int i = 0; i < 4; ++i)
#pragma unroll
    for (int j = 0; j < 4; ++j) acc[i][j] = zero4();
  const int rA = tid >> 3;
  const int cA = (tid & 7) * 8;
  for (int kt = 0; kt < K; kt += 64) {
#pragma unroll
    for (int i = 0; i < 4; ++i) {
      async16(A + (size_t)(row0 + i * 32 + rA) * K + kt + cA, As + i * 2048 + tid * 8);
      async16(B + (size_t)(col0 + i * 32 + rA) * K + kt + cA, Bs + i * 2048 + tid * 8);
    }
    __syncthreads();
#pragma unroll
    for (int kk = 0; kk < 2; ++kk) {
      v8s af[4], bfr[4];
#pragma unroll
      for (int i = 0; i < 4; ++i) {
        af[i]  = *(const v8s*)(As + (wm * 64 + i * 16 + ln) * 64 + kk * 32 + quad * 8);
        bfr[i] = *(const v8s*)(Bs + (wn * 64 + i * 16 + ln) * 64 + kk * 32 + quad * 8);
      }
#pragma unroll
      for (int i = 0; i < 4; ++i)
#pragma unroll
        for (int j = 0; j < 4; ++j)
          acc[i][j] = __builtin_amdgcn_mfma_f32_16x16x32_bf16(af[i], bfr[j], acc[i][j], 0, 0, 0);
    }
    __syncthreads();
  }
}

// ---------------- QKV GEMM + fused RoPE/reshape epilogue ----------------
__global__ __launch_bounds__(256) void gemm_qkv_rope(const u16* __restrict__ A,
                                                     const u16* __restrict__ B,
                                                     u16* __restrict__ Qh,
                                                     u16* __restrict__ Kh,
                                                     u16* __restrict__ Vt) {
  __shared__ __align__(16) u16 As[8192];
  __shared__ __align__(16) u16 Bs[8192];
  v4f acc[4][4];
  const int row0 = blockIdx.x * 128, col0 = blockIdx.y * 128;
  gemm_core(A, B, 1024, row0, col0, As, Bs, acc);
  const int tid = threadIdx.x, lane = tid & 63;
  const int wm = (tid >> 7) & 1, wn = (tid >> 6) & 1;
  const int ln = lane & 15, quad = lane >> 4;
  const int colbase = col0 + wn * 64;       // 64-aligned => one head per wave
  const int seg = colbase >> 10;            // 0=q 1=k 2=v
  const int h = (colbase & 1023) >> 6;
  if (seg < 2) {
    u16* dst = (seg == 0) ? Qh : Kh;
#pragma unroll
    for (int i = 0; i < 4; ++i) {
#pragma unroll
      for (int r = 0; r < 4; ++r) {
        int row = row0 + wm * 64 + i * 16 + quad * 4 + r;
        int b = row >> 11, t = row & 2047;
        size_t base = ((size_t)(b * 16 + h) * 2048 + t) * 64;
#pragma unroll
        for (int j = 0; j < 2; ++j) {
          int d1 = j * 16 + ln;  // 0..31
          float theta = exp2f((float)d1 * -0.4152410118609203f);  // 10000^(-d1/32)
          float sn, cs;
          fast_sincos((float)t * theta, &sn, &cs);
          float v1 = acc[i][j][r], v2 = acc[i][j + 2][r];
          dst[base + d1]      = f2bf(v1 * cs - v2 * sn);
          dst[base + d1 + 32] = f2bf(v2 * cs + v1 * sn);
        }
      }
    }
  } else {
#pragma unroll
    for (int i = 0; i < 4; ++i)
#pragma unroll
      for (int j = 0; j < 4; ++j) {
        int d = j * 16 + ln;
#pragma unroll
        for (int r = 0; r < 4; ++r) {
          int row = row0 + wm * 64 + i * 16 + quad * 4 + r;
          int b = row >> 11, t = row & 2047;
          Vt[((size_t)(b * 16 + h) * 64 + d) * 2048 + t] = f2bf(acc[i][j][r]);
        }
      }
  }
}

// ---------------- output GEMM ----------------
__global__ __launch_bounds__(256) void gemm_out_k(const u16* __restrict__ A,
                                                  const u16* __restrict__ B,
                                                  float* __restrict__ C) {
  __shared__ __align__(16) u16 As[8192];
  __shared__ __align__(16) u16 Bs[8192];
  v4f acc[4][4];
  const int row0 = blockIdx.x * 128, col0 = blockIdx.y * 128;
  gemm_core(A, B, 1024, row0, col0, As, Bs, acc);
  const int tid = threadIdx.x, lane = tid & 63;
  const int wm = (tid >> 7) & 1, wn = (tid >> 6) & 1;
  const int ln = lane & 15, quad = lane >> 4;
#pragma unroll
  for (int i = 0; i < 4; ++i)
#pragma unroll
    for (int r = 0; r < 4; ++r) {
      int row = row0 + wm * 64 + i * 16 + quad * 4 + r;
#pragma unroll
      for (int j = 0; j < 4; ++j) {
        int col = col0 + wn * 64 + j * 16 + ln;
        C[(size_t)row * 1024 + col] = acc[i][j][r];
      }
    }
}

// ---------------- causal flash attention v2 ----------------
// S^T = K·Q^T trick: mfma(Kfrag, Qfrag) -> C col=lane&15=q, row=quad*4+r=key.
// Softmax rows live per-lane (q = ln), reduction = in-lane + 2 shuffles.
// PV as mfma(Vtfrag, Pfrag) -> O^T layout, alpha stays per-lane.
// Block: 4 waves x 32 q-rows = 128 q-rows; key tile 64; 2 barriers/tile.
#define PS_STRIDE 72   // 64 + 8 u16 pad: 16B-aligned rows, 2-way bank alias (free)

template <bool MASKED>
__device__ __forceinline__ void flash_tile(const u16* Ks, const u16* Vs, u16* Pw,
                                           const v8s aq[2][2], v4f od[2][4],
                                           float m[2], float l[2],
                                           int s0, int q0, int ln, int quad) {
  const float SCL = 0.125f * 1.4426950408889634f;  // 1/sqrt(64) * log2(e)
  v8s ak[4][2];
#pragma unroll
  for (int kf = 0; kf < 4; ++kf)
#pragma unroll
    for (int kk = 0; kk < 2; ++kk)
      ak[kf][kk] = *(const v8s*)(Ks + (kf * 16 + ln) * 64 + kk * 32 + quad * 8);
#pragma unroll
  for (int qt = 0; qt < 2; ++qt) {
    v4f sc[4];
#pragma unroll
    for (int kf = 0; kf < 4; ++kf) sc[kf] = zero4();
#pragma unroll
    for (int kk = 0; kk < 2; ++kk)
#pragma unroll
      for (int kf = 0; kf < 4; ++kf)
        sc[kf] = __builtin_amdgcn_mfma_f32_16x16x32_bf16(ak[kf][kk], aq[qt][kk], sc[kf], 0, 0, 0);
    float s[4][4];
    float tm = -3.0e38f;
#pragma unroll
    for (int kf = 0; kf < 4; ++kf)
#pragma unroll
      for (int r = 0; r < 4; ++r) {
        float v = sc[kf][r] * SCL;
        if (MASKED) {
          int key = s0 + kf * 16 + quad * 4 + r;
          v = (key <= q0 + qt * 16 + ln) ? v : -3.0e38f;
        }
        s[kf][r] = v;
        tm = fmaxf(tm, v);
      }
    tm = fmaxf(tm, __shfl_xor(tm, 16));
    tm = fmaxf(tm, __shfl_xor(tm, 32));
    float mn = fmaxf(m[qt], tm);
    float al = exp2f(m[qt] - mn);
    m[qt] = mn;
    float ls = 0.f;
#pragma unroll
    for (int kf = 0; kf < 4; ++kf) {
      float p0 = exp2f(s[kf][0] - mn), p1 = exp2f(s[kf][1] - mn);
      float p2 = exp2f(s[kf][2] - mn), p3 = exp2f(s[kf][3] - mn);
      ls += (p0 + p1) + (p2 + p3);
      uint2 pk;
      pk.x = pk2bf(p0, p1);
      pk.y = pk2bf(p2, p3);
      *(uint2*)(Pw + (qt * 16 + ln) * PS_STRIDE + kf * 16 + quad * 4) = pk;
    }
    l[qt] = l[qt] * al + ls;
#pragma unroll
    for (int df = 0; df < 4; ++df)
#pragma unroll
      for (int r = 0; r < 4; ++r) od[qt][df][r] *= al;
  }
  // PV: lgkmcnt wait on Pw (same wave) is compiler-inserted; no barrier needed
  v8s bp[2][2], av[4][2];
#pragma unroll
  for (int qt = 0; qt < 2; ++qt)
#pragma unroll
    for (int kk = 0; kk < 2; ++kk)
      bp[qt][kk] = *(const v8s*)(Pw + (qt * 16 + ln) * PS_STRIDE + kk * 32 + quad * 8);
#pragma unroll
  for (int df = 0; df < 4; ++df)
#pragma unroll
    for (int kk = 0; kk < 2; ++kk)
      av[df][kk] = *(const v8s*)(Vs + (df * 16 + ln) * 64 + kk * 32 + quad * 8);
#pragma unroll
  for (int qt = 0; qt < 2; ++qt)
#pragma unroll
    for (int df = 0; df < 4; ++df)
#pragma unroll
      for (int kk = 0; kk < 2; ++kk)
        od[qt][df] = __builtin_amdgcn_mfma_f32_16x16x32_bf16(av[df][kk], bp[qt][kk], od[qt][df], 0, 0, 0);
}

__global__ __launch_bounds__(256, 4) void flash_k(const u16* __restrict__ Q,
                                                  const u16* __restrict__ Kh,
                                                  const u16* __restrict__ V,
                                                  u16* __restrict__ O) {
  __shared__ __align__(16) u16 Ks[64 * 64];
  __shared__ __align__(16) u16 Vs[64 * 64];
  __shared__ __align__(16) u16 Ps[4 * 32 * PS_STRIDE];
  const int tid = threadIdx.x;
  const int lane = tid & 63, w = tid >> 6;
  const int ln = lane & 15, quad = lane >> 4;
  const int qi = 15 - blockIdx.x;        // heavy blocks first
  const int bh = blockIdx.y;
  const int b = bh >> 4, h = bh & 15;
  const int qb = qi * 128;
  const int q0 = qb + w * 32;
  const size_t qoff = (size_t)bh * 2048 * 64;
  u16* Pw = Ps + w * 32 * PS_STRIDE;

  v8s aq[2][2];
#pragma unroll
  for (int qt = 0; qt < 2; ++qt)
#pragma unroll
    for (int kk = 0; kk < 2; ++kk)
      aq[qt][kk] = *(const v8s*)(Q + qoff + (size_t)(q0 + qt * 16 + ln) * 64 + kk * 32 + quad * 8);

  float m[2] = {-3.0e38f, -3.0e38f};
  float l[2] = {0.f, 0.f};
  v4f od[2][4];
#pragma unroll
  for (int qt = 0; qt < 2; ++qt)
#pragma unroll
    for (int df = 0; df < 4; ++df) od[qt][df] = zero4();

  const int rS = tid >> 3;
  const int cS = (tid & 7) * 8;
  const u16* Kbase = Kh + qoff;
  const u16* Vbase = V + (size_t)bh * 131072;

  for (int s0 = 0; s0 < qb + 128; s0 += 64) {
    async16(Kbase + (size_t)(s0 + rS) * 64 + cS, Ks + tid * 8);
    async16(Kbase + (size_t)(s0 + 32 + rS) * 64 + cS, Ks + 2048 + tid * 8);
    async16(Vbase + (size_t)rS * 2048 + s0 + cS, Vs + tid * 8);
    async16(Vbase + (size_t)(rS + 32) * 2048 + s0 + cS, Vs + 2048 + tid * 8);
    __syncthreads();
    if (s0 >= qb)
      flash_tile<true>(Ks, Vs, Pw, aq, od, m, l, s0, q0, ln, quad);
    else
      flash_tile<false>(Ks, Vs, Pw, aq, od, m, l, s0, q0, ln, quad);
    __syncthreads();
  }

#pragma unroll
  for (int qt = 0; qt < 2; ++qt) {
    float lt = l[qt];
    lt += __shfl_xor(lt, 16);
    lt += __shfl_xor(lt, 32);
    float inv = 1.0f / lt;
    int t = q0 + qt * 16 + ln;
    size_t obase = ((size_t)b * 2048 + t) * 1024 + h * 64;
#pragma unroll
    for (int df = 0; df < 4; ++df) {
      ushort4 o;
      o.x = f2bf(od[qt][df][0] * inv);
      o.y = f2bf(od[qt][df][1] * inv);
      o.z = f2bf(od[qt][df][2] * inv);
      o.w = f2bf(od[qt][df][3] * inv);
      *(ushort4*)(O + obase + df * 16 + quad * 4) = o;
    }
  }
}

extern "C" void kernel_launch(void* const* d_in, const int* in_sizes, int n_in,
                              void* d_out, int out_size, void* d_ws, size_t ws_size,
                              hipStream_t stream) {
  const float* x     = (const float*)d_in[0];
  const float* w_qkv = (const float*)d_in[1];
  const float* w_out = (const float*)d_in[2];
  float* out = (float*)d_out;
  char* ws = (char*)d_ws;
  u16* xb    = (u16*)(ws);              // 16 MB
  u16* wqkvb = (u16*)(ws + 16777216);   // 6 MB
  u16* woutb = (u16*)(ws + 23068672);   // 2 MB
  u16* qh    = (u16*)(ws + 25165824);   // [64][2048][64]
  u16* kh    = (u16*)(ws + 41943040);   // [64][2048][64]
  u16* vt    = (u16*)(ws + 58720256);   // [64][64][2048]
  u16* oa    = (u16*)(ws + 75497472);   // [8192][1024]

  cast_bf16_k<<<8192, 256, 0, stream>>>(x, xb, 2097152);
  cast_bf16_k<<<3072, 256, 0, stream>>>(w_qkv, wqkvb, 786432);
  cast_bf16_k<<<1024, 256, 0, stream>>>(w_out, woutb, 262144);
  gemm_qkv_rope<<<dim3(64, 24), 256, 0, stream>>>(xb, wqkvb, qh, kh, vt);
  flash_k<<<dim3(16, 64), 256, 0, stream>>>(qh, kh, vt, oa);
  gemm_out_k<<<dim3(64, 8), 256, 0, stream>>>(oa, woutb, out);
}

// Round 3
// 371.166 us; speedup vs baseline: 1.5167x; 1.5145x over previous
//
#include <hip/hip_runtime.h>

typedef unsigned short u16;
typedef __attribute__((ext_vector_type(8))) short v8s;   // 8 x bf16 MFMA operand
typedef __attribute__((ext_vector_type(4))) float v4f;   // MFMA accumulator

__device__ __forceinline__ u16 f2bf(float f) {
  unsigned u = __float_as_uint(f);
  u += 0x7FFF + ((u >> 16) & 1);   // RNE
  return (u16)(u >> 16);
}

// pack two floats -> {hi.bf16, lo.bf16} u32 (round-half-up, fine at this scale)
__device__ __forceinline__ unsigned pk2bf(float lo, float hi) {
  unsigned a = __float_as_uint(lo) + 0x8000u;
  unsigned b = __float_as_uint(hi) + 0x8000u;
  return __builtin_amdgcn_perm(b, a, 0x07060302);
}

__device__ __forceinline__ v4f zero4() {
  v4f z; z[0] = 0.f; z[1] = 0.f; z[2] = 0.f; z[3] = 0.f; return z;
}

__device__ __forceinline__ void async16(const u16* g, u16* l) {
  __builtin_amdgcn_global_load_lds(
      (const __attribute__((address_space(1))) unsigned int*)g,
      (__attribute__((address_space(3))) unsigned int*)l, 16, 0, 0);
}

// reduce x to [-pi,pi] then native sin/cos (v_sin valid range)
__device__ __forceinline__ void fast_sincos(float x, float* s, float* c) {
  float k = rintf(x * 0.15915494309189535f);
  float r = __builtin_fmaf(k, -6.28125f, x);
  r = __builtin_fmaf(k, -0.0019353071795864769f, r);
  *s = __sinf(r);
  *c = __cosf(r);
}

// ---------------- fp32 -> bf16 cast ----------------
__global__ __launch_bounds__(256) void cast_bf16_k(const float* __restrict__ s,
                                                   u16* __restrict__ d, int n4) {
  int i = blockIdx.x * 256 + threadIdx.x;
  if (i >= n4) return;
  float4 v = ((const float4*)s)[i];
  ((ushort4*)d)[i] = make_ushort4(f2bf(v.x), f2bf(v.y), f2bf(v.z), f2bf(v.w));
}

// ---------------- shared GEMM mainloop ----------------
// C(128x128) = A[M,K] @ B[N,K]^T   (both bf16 row-major, K multiple of 64)
__device__ __forceinline__ void gemm_core(const u16* __restrict__ A,
                                          const u16* __restrict__ B, int K,
                                          int row0, int col0, u16* As, u16* Bs,
                                          v4f acc[4][4]) {
  const int tid = threadIdx.x;
  const int lane = tid & 63;
  const int wm = (tid >> 7) & 1;
  const int wn = (tid >> 6) & 1;
  const int ln = lane & 15, quad = lane >> 4;
#pragma unroll
  for (int i = 0; i < 4; ++i)
#pragma unroll
    for (int j = 0; j < 4; ++j) acc[i][j] = zero4();
  const int rA = tid >> 3;
  const int cA = (tid & 7) * 8;
  for (int kt = 0; kt < K; kt += 64) {
#pragma unroll
    for (int i = 0; i < 4; ++i) {
      async16(A + (size_t)(row0 + i * 32 + rA) * K + kt + cA, As + i * 2048 + tid * 8);
      async16(B + (size_t)(col0 + i * 32 + rA) * K + kt + cA, Bs + i * 2048 + tid * 8);
    }
    __syncthreads();
#pragma unroll
    for (int kk = 0; kk < 2; ++kk) {
      v8s af[4], bfr[4];
#pragma unroll
      for (int i = 0; i < 4; ++i) {
        af[i]  = *(const v8s*)(As + (wm * 64 + i * 16 + ln) * 64 + kk * 32 + quad * 8);
        bfr[i] = *(const v8s*)(Bs + (wn * 64 + i * 16 + ln) * 64 + kk * 32 + quad * 8);
      }
#pragma unroll
      for (int i = 0; i < 4; ++i)
#pragma unroll
        for (int j = 0; j < 4; ++j)
          acc[i][j] = __builtin_amdgcn_mfma_f32_16x16x32_bf16(af[i], bfr[j], acc[i][j], 0, 0, 0);
    }
    __syncthreads();
  }
}

// ---------------- QKV GEMM + fused RoPE/reshape epilogue ----------------
__global__ __launch_bounds__(256) void gemm_qkv_rope(const u16* __restrict__ A,
                                                     const u16* __restrict__ B,
                                                     u16* __restrict__ Qh,
                                                     u16* __restrict__ Kh,
                                                     u16* __restrict__ Vt) {
  __shared__ __align__(16) u16 As[8192];
  __shared__ __align__(16) u16 Bs[8192];
  v4f acc[4][4];
  const int row0 = blockIdx.x * 128, col0 = blockIdx.y * 128;
  gemm_core(A, B, 1024, row0, col0, As, Bs, acc);
  const int tid = threadIdx.x, lane = tid & 63;
  const int wm = (tid >> 7) & 1, wn = (tid >> 6) & 1;
  const int ln = lane & 15, quad = lane >> 4;
  const int colbase = col0 + wn * 64;       // 64-aligned => one head per wave
  const int seg = colbase >> 10;            // 0=q 1=k 2=v
  const int h = (colbase & 1023) >> 6;
  if (seg < 2) {
    u16* dst = (seg == 0) ? Qh : Kh;
#pragma unroll
    for (int i = 0; i < 4; ++i) {
#pragma unroll
      for (int r = 0; r < 4; ++r) {
        int row = row0 + wm * 64 + i * 16 + quad * 4 + r;
        int b = row >> 11, t = row & 2047;
        size_t base = ((size_t)(b * 16 + h) * 2048 + t) * 64;
#pragma unroll
        for (int j = 0; j < 2; ++j) {
          int d1 = j * 16 + ln;  // 0..31
          float theta = exp2f((float)d1 * -0.4152410118609203f);  // 10000^(-d1/32)
          float sn, cs;
          fast_sincos((float)t * theta, &sn, &cs);
          float v1 = acc[i][j][r], v2 = acc[i][j + 2][r];
          dst[base + d1]      = f2bf(v1 * cs - v2 * sn);
          dst[base + d1 + 32] = f2bf(v2 * cs + v1 * sn);
        }
      }
    }
  } else {
#pragma unroll
    for (int i = 0; i < 4; ++i)
#pragma unroll
      for (int j = 0; j < 4; ++j) {
        int d = j * 16 + ln;
#pragma unroll
        for (int r = 0; r < 4; ++r) {
          int row = row0 + wm * 64 + i * 16 + quad * 4 + r;
          int b = row >> 11, t = row & 2047;
          Vt[((size_t)(b * 16 + h) * 64 + d) * 2048 + t] = f2bf(acc[i][j][r]);
        }
      }
  }
}

// ---------------- output GEMM ----------------
__global__ __launch_bounds__(256) void gemm_out_k(const u16* __restrict__ A,
                                                  const u16* __restrict__ B,
                                                  float* __restrict__ C) {
  __shared__ __align__(16) u16 As[8192];
  __shared__ __align__(16) u16 Bs[8192];
  v4f acc[4][4];
  const int row0 = blockIdx.x * 128, col0 = blockIdx.y * 128;
  gemm_core(A, B, 1024, row0, col0, As, Bs, acc);
  const int tid = threadIdx.x, lane = tid & 63;
  const int wm = (tid >> 7) & 1, wn = (tid >> 6) & 1;
  const int ln = lane & 15, quad = lane >> 4;
#pragma unroll
  for (int i = 0; i < 4; ++i)
#pragma unroll
    for (int r = 0; r < 4; ++r) {
      int row = row0 + wm * 64 + i * 16 + quad * 4 + r;
#pragma unroll
      for (int j = 0; j < 4; ++j) {
        int col = col0 + wn * 64 + j * 16 + ln;
        C[(size_t)row * 1024 + col] = acc[i][j][r];
      }
    }
}

// ---------------- causal flash attention v3 (spill-free) ----------------
// S^T = K·Q^T: C col=lane&15=q, row=quad*4+r=key. Softmax per-lane + 2 shuffles.
// K/V fragments are STREAMED from LDS (not kept live) to stay under 128 VGPRs.
#define PS_STRIDE 72   // 64 + 8 u16 pad: 16B-aligned rows, 2-way bank alias (free)

template <bool MASKED>
__device__ __forceinline__ void flash_tile(const u16* Ks, const u16* Vs, u16* Pw,
                                           const v8s aq[2][2], v4f od[2][4],
                                           float m[2], float l[2],
                                           int s0, int q0, int ln, int quad) {
  const float SCL = 0.125f * 1.4426950408889634f;  // 1/sqrt(64) * log2(e)
  v4f sc[2][4];
#pragma unroll
  for (int qt = 0; qt < 2; ++qt)
#pragma unroll
    for (int kf = 0; kf < 4; ++kf) sc[qt][kf] = zero4();
  // QK^T: stream one K fragment at a time, feed both q-subtiles
#pragma unroll
  for (int kk = 0; kk < 2; ++kk)
#pragma unroll
    for (int kf = 0; kf < 4; ++kf) {
      v8s ak = *(const v8s*)(Ks + (kf * 16 + ln) * 64 + kk * 32 + quad * 8);
#pragma unroll
      for (int qt = 0; qt < 2; ++qt)
        sc[qt][kf] = __builtin_amdgcn_mfma_f32_16x16x32_bf16(ak, aq[qt][kk], sc[qt][kf], 0, 0, 0);
    }
  // online softmax, scores masked/scaled in place
#pragma unroll
  for (int qt = 0; qt < 2; ++qt) {
    const int qrow = q0 + qt * 16 + ln;
    float tm = -3.0e38f;
#pragma unroll
    for (int kf = 0; kf < 4; ++kf)
#pragma unroll
      for (int r = 0; r < 4; ++r) {
        float v = sc[qt][kf][r] * SCL;
        if (MASKED) {
          int key = s0 + kf * 16 + quad * 4 + r;
          v = (key <= qrow) ? v : -3.0e38f;
        }
        sc[qt][kf][r] = v;
        tm = fmaxf(tm, v);
      }
    tm = fmaxf(tm, __shfl_xor(tm, 16));
    tm = fmaxf(tm, __shfl_xor(tm, 32));
    float mn = fmaxf(m[qt], tm);
    float al = exp2f(m[qt] - mn);
    m[qt] = mn;
    float ls = 0.f;
#pragma unroll
    for (int kf = 0; kf < 4; ++kf) {
      float p0 = exp2f(sc[qt][kf][0] - mn), p1 = exp2f(sc[qt][kf][1] - mn);
      float p2 = exp2f(sc[qt][kf][2] - mn), p3 = exp2f(sc[qt][kf][3] - mn);
      ls += (p0 + p1) + (p2 + p3);
      uint2 pk;
      pk.x = pk2bf(p0, p1);
      pk.y = pk2bf(p2, p3);
      *(uint2*)(Pw + (qt * 16 + ln) * PS_STRIDE + kf * 16 + quad * 4) = pk;
    }
    l[qt] = l[qt] * al + ls;
#pragma unroll
    for (int df = 0; df < 4; ++df)
#pragma unroll
      for (int r = 0; r < 4; ++r) od[qt][df][r] *= al;
  }
  // PV: P round-trip is per-wave (lgkmcnt only, no barrier); stream V fragments
  v8s bp[2][2];
#pragma unroll
  for (int qt = 0; qt < 2; ++qt)
#pragma unroll
    for (int kk = 0; kk < 2; ++kk)
      bp[qt][kk] = *(const v8s*)(Pw + (qt * 16 + ln) * PS_STRIDE + kk * 32 + quad * 8);
#pragma unroll
  for (int kk = 0; kk < 2; ++kk)
#pragma unroll
    for (int df = 0; df < 4; ++df) {
      v8s av = *(const v8s*)(Vs + (df * 16 + ln) * 64 + kk * 32 + quad * 8);
#pragma unroll
      for (int qt = 0; qt < 2; ++qt)
        od[qt][df] = __builtin_amdgcn_mfma_f32_16x16x32_bf16(av, bp[qt][kk], od[qt][df], 0, 0, 0);
    }
}

__global__ __launch_bounds__(256, 3) void flash_k(const u16* __restrict__ Q,
                                                  const u16* __restrict__ Kh,
                                                  const u16* __restrict__ V,
                                                  u16* __restrict__ O) {
  __shared__ __align__(16) u16 Ks[64 * 64];
  __shared__ __align__(16) u16 Vs[64 * 64];
  __shared__ __align__(16) u16 Ps[4 * 32 * PS_STRIDE];
  const int tid = threadIdx.x;
  const int lane = tid & 63, w = tid >> 6;
  const int ln = lane & 15, quad = lane >> 4;
  const int qi = 15 - blockIdx.x;        // heavy blocks first
  const int bh = blockIdx.y;
  const int b = bh >> 4, h = bh & 15;
  const int qb = qi * 128;
  const int q0 = qb + w * 32;
  const size_t qoff = (size_t)bh * 2048 * 64;
  u16* Pw = Ps + w * 32 * PS_STRIDE;

  v8s aq[2][2];
#pragma unroll
  for (int qt = 0; qt < 2; ++qt)
#pragma unroll
    for (int kk = 0; kk < 2; ++kk)
      aq[qt][kk] = *(const v8s*)(Q + qoff + (size_t)(q0 + qt * 16 + ln) * 64 + kk * 32 + quad * 8);

  float m[2] = {-3.0e38f, -3.0e38f};
  float l[2] = {0.f, 0.f};
  v4f od[2][4];
#pragma unroll
  for (int qt = 0; qt < 2; ++qt)
#pragma unroll
    for (int df = 0; df < 4; ++df) od[qt][df] = zero4();

  const int rS = tid >> 3;
  const int cS = (tid & 7) * 8;
  const u16* Kbase = Kh + qoff;
  const u16* Vbase = V + (size_t)bh * 131072;

  for (int s0 = 0; s0 < qb + 128; s0 += 64) {
    async16(Kbase + (size_t)(s0 + rS) * 64 + cS, Ks + tid * 8);
    async16(Kbase + (size_t)(s0 + 32 + rS) * 64 + cS, Ks + 2048 + tid * 8);
    async16(Vbase + (size_t)rS * 2048 + s0 + cS, Vs + tid * 8);
    async16(Vbase + (size_t)(rS + 32) * 2048 + s0 + cS, Vs + 2048 + tid * 8);
    __syncthreads();
    if (s0 >= qb)
      flash_tile<true>(Ks, Vs, Pw, aq, od, m, l, s0, q0, ln, quad);
    else
      flash_tile<false>(Ks, Vs, Pw, aq, od, m, l, s0, q0, ln, quad);
    __syncthreads();
  }

#pragma unroll
  for (int qt = 0; qt < 2; ++qt) {
    float lt = l[qt];
    lt += __shfl_xor(lt, 16);
    lt += __shfl_xor(lt, 32);
    float inv = 1.0f / lt;
    int t = q0 + qt * 16 + ln;
    size_t obase = ((size_t)b * 2048 + t) * 1024 + h * 64;
#pragma unroll
    for (int df = 0; df < 4; ++df) {
      ushort4 o;
      o.x = f2bf(od[qt][df][0] * inv);
      o.y = f2bf(od[qt][df][1] * inv);
      o.z = f2bf(od[qt][df][2] * inv);
      o.w = f2bf(od[qt][df][3] * inv);
      *(ushort4*)(O + obase + df * 16 + quad * 4) = o;
    }
  }
}

extern "C" void kernel_launch(void* const* d_in, const int* in_sizes, int n_in,
                              void* d_out, int out_size, void* d_ws, size_t ws_size,
                              hipStream_t stream) {
  const float* x     = (const float*)d_in[0];
  const float* w_qkv = (const float*)d_in[1];
  const float* w_out = (const float*)d_in[2];
  float* out = (float*)d_out;
  char* ws = (char*)d_ws;
  u16* xb    = (u16*)(ws);              // 16 MB
  u16* wqkvb = (u16*)(ws + 16777216);   // 6 MB
  u16* woutb = (u16*)(ws + 23068672);   // 2 MB
  u16* qh    = (u16*)(ws + 25165824);   // [64][2048][64]
  u16* kh    = (u16*)(ws + 41943040);   // [64][2048][64]
  u16* vt    = (u16*)(ws + 58720256);   // [64][64][2048]
  u16* oa    = (u16*)(ws + 75497472);   // [8192][1024]

  cast_bf16_k<<<8192, 256, 0, stream>>>(x, xb, 2097152);
  cast_bf16_k<<<3072, 256, 0, stream>>>(w_qkv, wqkvb, 786432);
  cast_bf16_k<<<1024, 256, 0, stream>>>(w_out, woutb, 262144);
  gemm_qkv_rope<<<dim3(64, 24), 256, 0, stream>>>(xb, wqkvb, qh, kh, vt);
  flash_k<<<dim3(16, 64), 256, 0, stream>>>(qh, kh, vt, oa);
  gemm_out_k<<<dim3(64, 8), 256, 0, stream>>>(oa, woutb, out);
}

// Round 4
// 303.234 us; speedup vs baseline: 1.8565x; 1.2240x over previous
//
#include <hip/hip_runtime.h>

typedef unsigned short u16;
typedef __attribute__((ext_vector_type(8))) short v8s;   // 8 x bf16 MFMA operand
typedef __attribute__((ext_vector_type(4))) float v4f;   // MFMA accumulator

__device__ __forceinline__ u16 f2bf(float f) {
  unsigned u = __float_as_uint(f);
  u += 0x7FFF + ((u >> 16) & 1);   // RNE
  return (u16)(u >> 16);
}

// pack two floats -> {hi.bf16, lo.bf16} u32 (round-half-up, fine at this scale)
__device__ __forceinline__ unsigned pk2bf(float lo, float hi) {
  unsigned a = __float_as_uint(lo) + 0x8000u;
  unsigned b = __float_as_uint(hi) + 0x8000u;
  return __builtin_amdgcn_perm(b, a, 0x07060302);
}

__device__ __forceinline__ v4f zero4() {
  v4f z; z[0] = 0.f; z[1] = 0.f; z[2] = 0.f; z[3] = 0.f; return z;
}

__device__ __forceinline__ void async16(const u16* g, u16* l) {
  __builtin_amdgcn_global_load_lds(
      (const __attribute__((address_space(1))) unsigned int*)g,
      (__attribute__((address_space(3))) unsigned int*)l, 16, 0, 0);
}

// reduce x to [-pi,pi] then native sin/cos (v_sin valid range)
__device__ __forceinline__ void fast_sincos(float x, float* s, float* c) {
  float k = rintf(x * 0.15915494309189535f);
  float r = __builtin_fmaf(k, -6.28125f, x);
  r = __builtin_fmaf(k, -0.0019353071795864769f, r);
  *s = __sinf(r);
  *c = __cosf(r);
}

#define ATTN_SCL (0.125f * 1.4426950408889634f)  // 1/sqrt(64) * log2(e), folded into Q

// ---------------- fp32 -> bf16 cast ----------------
__global__ __launch_bounds__(256) void cast_bf16_k(const float* __restrict__ s,
                                                   u16* __restrict__ d, int n4) {
  int i = blockIdx.x * 256 + threadIdx.x;
  if (i >= n4) return;
  float4 v = ((const float4*)s)[i];
  ((ushort4*)d)[i] = make_ushort4(f2bf(v.x), f2bf(v.y), f2bf(v.z), f2bf(v.w));
}

// ---------------- shared GEMM mainloop ----------------
// C(128x128) = A[M,K] @ B[N,K]^T   (both bf16 row-major, K multiple of 64)
__device__ __forceinline__ void gemm_core(const u16* __restrict__ A,
                                          const u16* __restrict__ B, int K,
                                          int row0, int col0, u16* As, u16* Bs,
                                          v4f acc[4][4]) {
  const int tid = threadIdx.x;
  const int lane = tid & 63;
  const int wm = (tid >> 7) & 1;
  const int wn = (tid >> 6) & 1;
  const int ln = lane & 15, quad = lane >> 4;
#pragma unroll
  for (int i = 0; i < 4; ++i)
#pragma unroll
    for (int j = 0; j < 4; ++j) acc[i][j] = zero4();
  const int rA = tid >> 3;
  const int cA = (tid & 7) * 8;
  for (int kt = 0; kt < K; kt += 64) {
#pragma unroll
    for (int i = 0; i < 4; ++i) {
      async16(A + (size_t)(row0 + i * 32 + rA) * K + kt + cA, As + i * 2048 + tid * 8);
      async16(B + (size_t)(col0 + i * 32 + rA) * K + kt + cA, Bs + i * 2048 + tid * 8);
    }
    __syncthreads();
#pragma unroll
    for (int kk = 0; kk < 2; ++kk) {
      v8s af[4], bfr[4];
#pragma unroll
      for (int i = 0; i < 4; ++i) {
        af[i]  = *(const v8s*)(As + (wm * 64 + i * 16 + ln) * 64 + kk * 32 + quad * 8);
        bfr[i] = *(const v8s*)(Bs + (wn * 64 + i * 16 + ln) * 64 + kk * 32 + quad * 8);
      }
#pragma unroll
      for (int i = 0; i < 4; ++i)
#pragma unroll
        for (int j = 0; j < 4; ++j)
          acc[i][j] = __builtin_amdgcn_mfma_f32_16x16x32_bf16(af[i], bfr[j], acc[i][j], 0, 0, 0);
    }
    __syncthreads();
  }
}

// ---------------- QKV GEMM + fused RoPE/reshape epilogue ----------------
// q gets the softmax scale folded in (scale commutes with rotation)
__global__ __launch_bounds__(256) void gemm_qkv_rope(const u16* __restrict__ A,
                                                     const u16* __restrict__ B,
                                                     u16* __restrict__ Qh,
                                                     u16* __restrict__ Kh,
                                                     u16* __restrict__ Vt) {
  __shared__ __align__(16) u16 As[8192];
  __shared__ __align__(16) u16 Bs[8192];
  v4f acc[4][4];
  const int row0 = blockIdx.x * 128, col0 = blockIdx.y * 128;
  gemm_core(A, B, 1024, row0, col0, As, Bs, acc);
  const int tid = threadIdx.x, lane = tid & 63;
  const int wm = (tid >> 7) & 1, wn = (tid >> 6) & 1;
  const int ln = lane & 15, quad = lane >> 4;
  const int colbase = col0 + wn * 64;       // 64-aligned => one head per wave
  const int seg = colbase >> 10;            // 0=q 1=k 2=v
  const int h = (colbase & 1023) >> 6;
  if (seg < 2) {
    u16* dst = (seg == 0) ? Qh : Kh;
    const float oscl = (seg == 0) ? ATTN_SCL : 1.0f;
#pragma unroll
    for (int i = 0; i < 4; ++i) {
#pragma unroll
      for (int r = 0; r < 4; ++r) {
        int row = row0 + wm * 64 + i * 16 + quad * 4 + r;
        int b = row >> 11, t = row & 2047;
        size_t base = ((size_t)(b * 16 + h) * 2048 + t) * 64;
#pragma unroll
        for (int j = 0; j < 2; ++j) {
          int d1 = j * 16 + ln;  // 0..31
          float theta = exp2f((float)d1 * -0.4152410118609203f);  // 10000^(-d1/32)
          float sn, cs;
          fast_sincos((float)t * theta, &sn, &cs);
          float v1 = acc[i][j][r], v2 = acc[i][j + 2][r];
          dst[base + d1]      = f2bf((v1 * cs - v2 * sn) * oscl);
          dst[base + d1 + 32] = f2bf((v2 * cs + v1 * sn) * oscl);
        }
      }
    }
  } else {
#pragma unroll
    for (int i = 0; i < 4; ++i)
#pragma unroll
      for (int j = 0; j < 4; ++j) {
        int d = j * 16 + ln;
#pragma unroll
        for (int r = 0; r < 4; ++r) {
          int row = row0 + wm * 64 + i * 16 + quad * 4 + r;
          int b = row >> 11, t = row & 2047;
          Vt[((size_t)(b * 16 + h) * 64 + d) * 2048 + t] = f2bf(acc[i][j][r]);
        }
      }
  }
}

// ---------------- output GEMM ----------------
__global__ __launch_bounds__(256) void gemm_out_k(const u16* __restrict__ A,
                                                  const u16* __restrict__ B,
                                                  float* __restrict__ C) {
  __shared__ __align__(16) u16 As[8192];
  __shared__ __align__(16) u16 Bs[8192];
  v4f acc[4][4];
  const int row0 = blockIdx.x * 128, col0 = blockIdx.y * 128;
  gemm_core(A, B, 1024, row0, col0, As, Bs, acc);
  const int tid = threadIdx.x, lane = tid & 63;
  const int wm = (tid >> 7) & 1, wn = (tid >> 6) & 1;
  const int ln = lane & 15, quad = lane >> 4;
#pragma unroll
  for (int i = 0; i < 4; ++i)
#pragma unroll
    for (int r = 0; r < 4; ++r) {
      int row = row0 + wm * 64 + i * 16 + quad * 4 + r;
#pragma unroll
      for (int j = 0; j < 4; ++j) {
        int col = col0 + wn * 64 + j * 16 + ln;
        C[(size_t)row * 1024 + col] = acc[i][j][r];
      }
    }
}

// ---------------- causal flash attention v4 (balanced pairing) ----------------
// 32 q-tiles of 64 rows; block bx handles q-tile (31-bx) then (bx):
// (32-bx) + (bx+1) = 33 key-tiles per block — uniform work, no tail.
// S^T = K·Q^T layout trick; softmax per-lane + 2 shuffles; scale pre-folded in Q.
#define PS_STRIDE 72   // 64 + 8 u16 pad: 16B-aligned rows, 2-way bank alias (free)

template <bool MASKED>
__device__ __forceinline__ void flash_tile64(const u16* Ks, const u16* Vs, u16* Pw,
                                             const v8s aq[2], v4f od[4],
                                             float& m, float& l,
                                             int s0, int qrow, int ln, int quad) {
  v4f sc[4];
#pragma unroll
  for (int kf = 0; kf < 4; ++kf) sc[kf] = zero4();
#pragma unroll
  for (int kk = 0; kk < 2; ++kk)
#pragma unroll
    for (int kf = 0; kf < 4; ++kf) {
      v8s ak = *(const v8s*)(Ks + (kf * 16 + ln) * 64 + kk * 32 + quad * 8);
      sc[kf] = __builtin_amdgcn_mfma_f32_16x16x32_bf16(ak, aq[kk], sc[kf], 0, 0, 0);
    }
  float tm = -3.0e38f;
#pragma unroll
  for (int kf = 0; kf < 4; ++kf)
#pragma unroll
    for (int r = 0; r < 4; ++r) {
      float v = sc[kf][r];
      if (MASKED) {
        int key = s0 + kf * 16 + quad * 4 + r;
        v = (key <= qrow) ? v : -3.0e38f;
        sc[kf][r] = v;
      }
      tm = fmaxf(tm, v);
    }
  tm = fmaxf(tm, __shfl_xor(tm, 16));
  tm = fmaxf(tm, __shfl_xor(tm, 32));
  float mn = fmaxf(m, tm);
  float al = exp2f(m - mn);
  m = mn;
  float ls = 0.f;
#pragma unroll
  for (int kf = 0; kf < 4; ++kf) {
    float p0 = exp2f(sc[kf][0] - mn), p1 = exp2f(sc[kf][1] - mn);
    float p2 = exp2f(sc[kf][2] - mn), p3 = exp2f(sc[kf][3] - mn);
    ls += (p0 + p1) + (p2 + p3);
    uint2 pk;
    pk.x = pk2bf(p0, p1);
    pk.y = pk2bf(p2, p3);
    *(uint2*)(Pw + ln * PS_STRIDE + kf * 16 + quad * 4) = pk;
  }
  l = l * al + ls;
#pragma unroll
  for (int df = 0; df < 4; ++df)
#pragma unroll
    for (int r = 0; r < 4; ++r) od[df][r] *= al;
  // PV: P round-trip is per-wave (lgkmcnt only, no barrier); stream V fragments
  v8s bp[2];
#pragma unroll
  for (int kk = 0; kk < 2; ++kk)
    bp[kk] = *(const v8s*)(Pw + ln * PS_STRIDE + kk * 32 + quad * 8);
#pragma unroll
  for (int kk = 0; kk < 2; ++kk)
#pragma unroll
    for (int df = 0; df < 4; ++df) {
      v8s av = *(const v8s*)(Vs + (df * 16 + ln) * 64 + kk * 32 + quad * 8);
      od[df] = __builtin_amdgcn_mfma_f32_16x16x32_bf16(av, bp[kk], od[df], 0, 0, 0);
    }
}

__global__ __launch_bounds__(256, 4) void flash_k(const u16* __restrict__ Q,
                                                  const u16* __restrict__ Kh,
                                                  const u16* __restrict__ V,
                                                  u16* __restrict__ O) {
  __shared__ __align__(16) u16 Ks[64 * 64];
  __shared__ __align__(16) u16 Vs[64 * 64];
  __shared__ __align__(16) u16 Ps[4 * 16 * PS_STRIDE];
  const int tid = threadIdx.x;
  const int lane = tid & 63, w = tid >> 6;
  const int ln = lane & 15, quad = lane >> 4;
  const int bx = blockIdx.x;
  const int bh = blockIdx.y;
  const int b = bh >> 4, h = bh & 15;
  const size_t qoff = (size_t)bh * 2048 * 64;
  u16* Pw = Ps + w * 16 * PS_STRIDE;

  const int rS = tid >> 3;
  const int cS = (tid & 7) * 8;
  const u16* Kbase = Kh + qoff;
  const u16* Vbase = V + (size_t)bh * 131072;

#pragma unroll
  for (int ph = 0; ph < 2; ++ph) {
    const int qt_idx = ph ? bx : 31 - bx;   // heavy tile first
    const int q0 = qt_idx * 64 + w * 16;
    const int qrow = q0 + ln;
    v8s aq[2];
#pragma unroll
    for (int kk = 0; kk < 2; ++kk)
      aq[kk] = *(const v8s*)(Q + qoff + (size_t)(q0 + ln) * 64 + kk * 32 + quad * 8);
    float m = -3.0e38f, l = 0.f;
    v4f od[4];
#pragma unroll
    for (int df = 0; df < 4; ++df) od[df] = zero4();

    const int nt = qt_idx + 1;
    for (int it = 0; it < nt; ++it) {
      const int s0 = it * 64;
      async16(Kbase + (size_t)(s0 + rS) * 64 + cS, Ks + tid * 8);
      async16(Kbase + (size_t)(s0 + 32 + rS) * 64 + cS, Ks + 2048 + tid * 8);
      async16(Vbase + (size_t)rS * 2048 + s0 + cS, Vs + tid * 8);
      async16(Vbase + (size_t)(rS + 32) * 2048 + s0 + cS, Vs + 2048 + tid * 8);
      __syncthreads();
      if (it == nt - 1)
        flash_tile64<true>(Ks, Vs, Pw, aq, od, m, l, s0, qrow, ln, quad);
      else
        flash_tile64<false>(Ks, Vs, Pw, aq, od, m, l, s0, qrow, ln, quad);
      __syncthreads();
    }

    float lt = l;
    lt += __shfl_xor(lt, 16);
    lt += __shfl_xor(lt, 32);
    float inv = 1.0f / lt;
    int t = q0 + ln;
    size_t obase = ((size_t)b * 2048 + t) * 1024 + h * 64;
#pragma unroll
    for (int df = 0; df < 4; ++df) {
      ushort4 o;
      o.x = f2bf(od[df][0] * inv);
      o.y = f2bf(od[df][1] * inv);
      o.z = f2bf(od[df][2] * inv);
      o.w = f2bf(od[df][3] * inv);
      *(ushort4*)(O + obase + df * 16 + quad * 4) = o;
    }
  }
}

extern "C" void kernel_launch(void* const* d_in, const int* in_sizes, int n_in,
                              void* d_out, int out_size, void* d_ws, size_t ws_size,
                              hipStream_t stream) {
  const float* x     = (const float*)d_in[0];
  const float* w_qkv = (const float*)d_in[1];
  const float* w_out = (const float*)d_in[2];
  float* out = (float*)d_out;
  char* ws = (char*)d_ws;
  u16* xb    = (u16*)(ws);              // 16 MB
  u16* wqkvb = (u16*)(ws + 16777216);   // 6 MB
  u16* woutb = (u16*)(ws + 23068672);   // 2 MB
  u16* qh    = (u16*)(ws + 25165824);   // [64][2048][64]
  u16* kh    = (u16*)(ws + 41943040);   // [64][2048][64]
  u16* vt    = (u16*)(ws + 58720256);   // [64][64][2048]
  u16* oa    = (u16*)(ws + 75497472);   // [8192][1024]

  cast_bf16_k<<<8192, 256, 0, stream>>>(x, xb, 2097152);
  cast_bf16_k<<<3072, 256, 0, stream>>>(w_qkv, wqkvb, 786432);
  cast_bf16_k<<<1024, 256, 0, stream>>>(w_out, woutb, 262144);
  gemm_qkv_rope<<<dim3(64, 24), 256, 0, stream>>>(xb, wqkvb, qh, kh, vt);
  flash_k<<<dim3(16, 64), 256, 0, stream>>>(qh, kh, vt, oa);
  gemm_out_k<<<dim3(64, 8), 256, 0, stream>>>(oa, woutb, out);
}